// Round 1
// baseline (336.015 us; speedup 1.0000x reference)
//
#include <hip/hip_runtime.h>

// LightGCN: final = (x0 + x1 + x2 + x3) / 4, x_{l+1}[r] = sum_{e:row=r} x_l[col_e]*norm_e
// norm_e = rsqrt(deg[row_e]) * rsqrt(deg[col_e]), deg = clip(bincount(row),1)
// N = 150000 nodes, d = 64, E = 2.4M edges. Output fp32.
//
// R13 = R12 resubmit (GPU broker timeout, no bench ran; kernel unchanged):
// paired int2 scol loads (rows padded to even starts), int2 be[] bounds,
// float2 packed accumulation, init fused into fine's epilogue.

#define NUM_USERS 100000
#define NUM_ITEMS 50000
#define EMBED_DIM 64
#define N_NODES   150000
#define N_EDGES   2400000
#define N_BUCKETS 1172      // ceil(150000/128), 128 rows per bucket
#define PART_BLOCKS 256

// ws layout (byte offsets):
#define OFF_BHIST   0          // int32 x 1172
#define OFF_BBASE   8192       // int32 x 1172
#define OFF_BCURSOR 16384      // int32 x 1172
#define OFF_BE      24576      // int2  x N  {beg,end}        (ends 1224576)
#define OFF_RSQD    1224576    // f32 x N  rsqrt(max(deg,1))
#define OFF_SDEG    1824576    // f32 x N  sqrt(max(deg,1))
#define OFF_SCOL    2424576    // int32 x ~2.56M (padded)     (ends ~12629328)
#define OFF_XA      12633088   // bf16 x (N+1)*64 = 19200128  (ends 31833216)
#define OFF_XB      31833216   // bf16 x (N+1)*64             (aliased as `packed`)

__device__ __forceinline__ unsigned f2bf(float f) {  // RNE fp32 -> bf16 (as u16)
    unsigned u = __float_as_uint(f);
    return (u + 0x7fffu + ((u >> 16) & 1u)) >> 16;
}
__device__ __forceinline__ float bflo(unsigned u) { return __uint_as_float(u << 16); }
__device__ __forceinline__ float bfhi(unsigned u) { return __uint_as_float(u & 0xffff0000u); }
__device__ __forceinline__ float2 bf2(unsigned u) {  // bf16 pair -> float2
    float2 r; r.x = bflo(u); r.y = bfhi(u); return r;
}

// Pass 1: block-aggregated bucket histogram, int4 edge reads.
__global__ void bhist_kernel(const int4* __restrict__ row4, int* __restrict__ bhist) {
    __shared__ int lh[N_BUCKETS];
    for (int t = threadIdx.x; t < N_BUCKETS; t += blockDim.x) lh[t] = 0;
    __syncthreads();
    const int total4 = N_EDGES / 4;
    for (int i = blockIdx.x * blockDim.x + threadIdx.x; i < total4; i += gridDim.x * blockDim.x) {
        int4 r = row4[i];
        atomicAdd(&lh[r.x >> 7], 1);
        atomicAdd(&lh[r.y >> 7], 1);
        atomicAdd(&lh[r.z >> 7], 1);
        atomicAdd(&lh[r.w >> 7], 1);
    }
    __syncthreads();
    for (int t = threadIdx.x; t < N_BUCKETS; t += blockDim.x)
        if (lh[t]) atomicAdd(&bhist[t], lh[t]);
}

// Pass 2: exclusive scan of PADDED bucket strides -> bbase/bcursor (all even);
// stride(b) = even(bhist[b]) + 128 (room for per-row even padding). Idle
// threads zero the dummy rows (index N) of both bf16 tables.
__global__ void bscan_kernel(const int* __restrict__ bhist, int* __restrict__ bbase,
                             int* __restrict__ bcursor,
                             uint2* __restrict__ yA, uint2* __restrict__ yB) {
    __shared__ int lds[1024];
    __shared__ int carry_s;
    if (threadIdx.x < 16) {                 // dummy row N_NODES: 16 uint2 per table
        uint2 z; z.x = 0u; z.y = 0u;
        yA[2400000 + threadIdx.x] = z;
        yB[2400000 + threadIdx.x] = z;
    }
    if (threadIdx.x == 0) carry_s = 0;
    __syncthreads();
    for (int base = 0; base < N_BUCKETS; base += 1024) {
        int i = base + (int)threadIdx.x;
        int v = (i < N_BUCKETS) ? (((bhist[i] + 1) & ~1) + 128) : 0;
        lds[threadIdx.x] = v;
        __syncthreads();
        for (int off = 1; off < 1024; off <<= 1) {
            int t = (threadIdx.x >= off) ? lds[threadIdx.x - off] : 0;
            __syncthreads();
            lds[threadIdx.x] += t;
            __syncthreads();
        }
        int incl = lds[threadIdx.x];
        int excl = incl - v + carry_s;
        if (i < N_BUCKETS) { bbase[i] = excl; bcursor[i] = excl; }
        __syncthreads();
        if (threadIdx.x == 1023) carry_s += incl;
        __syncthreads();
    }
}

// Pass 3: partition, int4 edge reads. Per-block LDS hist -> one reservation
// atomic per bucket -> streamed scatter. pack = (row&127)<<18 | col (col<2^18).
__global__ void partition_kernel(const int4* __restrict__ row4, const int4* __restrict__ col4,
                                 int* __restrict__ bcursor, unsigned* __restrict__ packed) {
    __shared__ int lh[N_BUCKETS];
    for (int t = threadIdx.x; t < N_BUCKETS; t += blockDim.x) lh[t] = 0;
    __syncthreads();
    const int total4 = N_EDGES / 4;
    int per4 = (total4 + gridDim.x - 1) / gridDim.x;
    int s4 = blockIdx.x * per4;
    int e4 = s4 + per4; if (e4 > total4) e4 = total4;
    for (int i = s4 + (int)threadIdx.x; i < e4; i += (int)blockDim.x) {
        int4 r = row4[i];
        atomicAdd(&lh[r.x >> 7], 1);
        atomicAdd(&lh[r.y >> 7], 1);
        atomicAdd(&lh[r.z >> 7], 1);
        atomicAdd(&lh[r.w >> 7], 1);
    }
    __syncthreads();
    for (int t = threadIdx.x; t < N_BUCKETS; t += blockDim.x) {
        int c = lh[t];
        lh[t] = c ? atomicAdd(&bcursor[t], c) : 0;   // lh becomes the block's write cursor
    }
    __syncthreads();
    for (int i = s4 + (int)threadIdx.x; i < e4; i += (int)blockDim.x) {
        int4 r = row4[i];
        int4 c = col4[i];
        int pos;
        pos = atomicAdd(&lh[r.x >> 7], 1); packed[pos] = ((unsigned)(r.x & 127) << 18) | (unsigned)c.x;
        pos = atomicAdd(&lh[r.y >> 7], 1); packed[pos] = ((unsigned)(r.y & 127) << 18) | (unsigned)c.y;
        pos = atomicAdd(&lh[r.z >> 7], 1); packed[pos] = ((unsigned)(r.z & 127) << 18) | (unsigned)c.z;
        pos = atomicAdd(&lh[r.w >> 7], 1); packed[pos] = ((unsigned)(r.w & 127) << 18) | (unsigned)c.w;
    }
}

// Pass 4: one block per bucket. LDS 128-row histogram, even-padded row starts,
// be/rsqd/sdeg, in-window scatter to row-sorted scol, and y0 = x0*rsqd rows.
__global__ void fine_kernel(const int* __restrict__ bbase, const int* __restrict__ bhist,
                            const unsigned* __restrict__ packed,
                            int2* __restrict__ be,
                            float* __restrict__ rsqd, float* __restrict__ sdeg,
                            int* __restrict__ scol,
                            const float4* __restrict__ user, const float4* __restrict__ item,
                            uint2* __restrict__ yA) {
    __shared__ int rh[128];
    __shared__ int rsc[128];
    __shared__ int rcur[128];
    __shared__ float rq[128];
    int b = blockIdx.x;
    int base = bbase[b];
    int cnt  = bhist[b];
    if (threadIdx.x < 128) rh[threadIdx.x] = 0;
    __syncthreads();
    for (int i = threadIdx.x; i < cnt; i += blockDim.x)
        atomicAdd(&rh[packed[base + i] >> 18], 1);
    __syncthreads();
    if (threadIdx.x < 128) rsc[threadIdx.x] = (rh[threadIdx.x] + 1) & ~1;  // even size
    __syncthreads();
    for (int off = 1; off < 128; off <<= 1) {
        int t = (threadIdx.x < 128 && threadIdx.x >= off) ? rsc[threadIdx.x - off] : 0;
        __syncthreads();
        if (threadIdx.x < 128) rsc[threadIdx.x] += t;
        __syncthreads();
    }
    if (threadIdx.x < 128) {
        int r = threadIdx.x;
        int sz = (rh[r] + 1) & ~1;
        int pstart = rsc[r] - sz;            // even
        rcur[r] = pstart;
        int n = (b << 7) + r;
        if (n < N_NODES) {
            int2 p; p.x = base + pstart; p.y = base + pstart + rh[r];
            be[n] = p;
            float d = (float)(rh[r] < 1 ? 1 : rh[r]);
            float rn = rsqrtf(d);
            rq[r] = rn;
            rsqd[n] = rn;
            sdeg[n] = sqrtf(d);
        }
    }
    __syncthreads();
    for (int i = threadIdx.x; i < cnt; i += blockDim.x) {
        unsigned p = packed[base + i];
        int pos = atomicAdd(&rcur[p >> 18], 1);       // LDS atomic
        scol[base + pos] = (int)(p & 0x3FFFFu);
    }
    // y0 rows for this bucket: 128 rows x 16 uint2 words; word w covers float4 w.
    for (int idx = threadIdx.x; idx < 2048; idx += blockDim.x) {
        int r = idx >> 4, w = idx & 15;
        int n = (b << 7) + r;
        if (n < N_NODES) {
            const float4* src = (n < NUM_USERS) ? (user + (size_t)n * 16)
                                                : (item + (size_t)(n - NUM_USERS) * 16);
            float4 v = src[w];
            float rn = rq[r];
            uint2 o;
            o.x = f2bf(v.x * rn) | (f2bf(v.y * rn) << 16);
            o.y = f2bf(v.z * rn) | (f2bf(v.w * rn) << 16);
            yA[(size_t)n * 16 + w] = o;
        }
    }
}

// One wave per node. lane = 8*g + q: g = edge pair-group (0..7), q = dim oct.
// Each iter: 16 edges via one int2 scol load per lane + 2 uint4 bf16 gathers.
// float2 sums -> v_pk_add_f32. Invalid slots select the dummy zero row.
__device__ __forceinline__ void pull_body(int n, int lane, const int2* be,
                                          const int2* scol2, const uint4* xin, float2 sum[4]) {
    int g = lane >> 3;
    int q = lane & 7;
    int2 bnd = be[n];
    int j = bnd.x, endj = bnd.y;       // j even by construction
    for (; j < endj; j += 16) {
        int p0 = j + 2 * g;
        int2 cc = scol2[p0 >> 1];      // may read pad/next-row slots; discarded below
        int c0 = (p0     < endj) ? cc.x : N_NODES;
        int c1 = (p0 + 1 < endj) ? cc.y : N_NODES;
        uint4 X0 = xin[(size_t)c0 * 8 + q];
        uint4 X1 = xin[(size_t)c1 * 8 + q];
        sum[0] += bf2(X0.x) + bf2(X1.x);
        sum[1] += bf2(X0.y) + bf2(X1.y);
        sum[2] += bf2(X0.z) + bf2(X1.z);
        sum[3] += bf2(X0.w) + bf2(X1.w);
    }
    // reduce over the 8 edge groups (xor strides 8, 16, 32)
#pragma unroll
    for (int off = 8; off < 64; off <<= 1) {
#pragma unroll
        for (int k = 0; k < 4; ++k) {
            sum[k].x += __shfl_xor(sum[k].x, off);
            sum[k].y += __shfl_xor(sum[k].y, off);
        }
    }
}

// Middle layers: y_{l+1}[n] = rsqd[n]^2 * sum  (bf16).
__global__ void pull_kernel(const int2* __restrict__ be,
                            const int2* __restrict__ scol2, const float* __restrict__ rsqd,
                            const uint4* __restrict__ xin, uint4* __restrict__ xout) {
    int n = blockIdx.x * 4 + ((int)threadIdx.x >> 6);
    if (n >= N_NODES) return;
    int lane = threadIdx.x & 63;
    float2 sum[4];
    sum[0] = make_float2(0.f, 0.f); sum[1] = make_float2(0.f, 0.f);
    sum[2] = make_float2(0.f, 0.f); sum[3] = make_float2(0.f, 0.f);
    pull_body(n, lane, be, scol2, xin, sum);
    if ((lane >> 3) == 0) {
        int q = lane & 7;
        float rn = rsqd[n];
        float s2 = rn * rn;
        uint4 p;
        p.x = f2bf(sum[0].x * s2) | (f2bf(sum[0].y * s2) << 16);
        p.y = f2bf(sum[1].x * s2) | (f2bf(sum[1].y * s2) << 16);
        p.z = f2bf(sum[2].x * s2) | (f2bf(sum[2].y * s2) << 16);
        p.w = f2bf(sum[3].x * s2) | (f2bf(sum[3].y * s2) << 16);
        xout[(size_t)n * 8 + q] = p;
    }
}

// Last layer: acc = (x0 + (y1+y2)*sdeg + rsqd*sum) / 4.
__global__ void pull_last_kernel(const int2* __restrict__ be,
                                 const int2* __restrict__ scol2, const float* __restrict__ rsqd,
                                 const float* __restrict__ sdeg,
                                 const uint4* __restrict__ xin,   // y2 (gather table)
                                 const uint4* __restrict__ xprev, // y1
                                 const float4* __restrict__ user, const float4* __restrict__ item,
                                 float4* __restrict__ acc4) {
    int n = blockIdx.x * 4 + ((int)threadIdx.x >> 6);
    if (n >= N_NODES) return;
    int lane = threadIdx.x & 63;
    float2 sum[4];
    sum[0] = make_float2(0.f, 0.f); sum[1] = make_float2(0.f, 0.f);
    sum[2] = make_float2(0.f, 0.f); sum[3] = make_float2(0.f, 0.f);
    pull_body(n, lane, be, scol2, xin, sum);
    if ((lane >> 3) == 0) {
        int q = lane & 7;
        float rn = rsqd[n];
        float sd = sdeg[n];
        uint4 p2 = xin  [(size_t)n * 8 + q];
        uint4 p1 = xprev[(size_t)n * 8 + q];
        const float4* x0 = (n < NUM_USERS) ? (user + (size_t)n * 16)
                                           : (item + (size_t)(n - NUM_USERS) * 16);
        float4 a0 = x0[q * 2], a1 = x0[q * 2 + 1];
        float4 o0, o1;
        o0.x = (a0.x + (bflo(p1.x) + bflo(p2.x)) * sd + rn * sum[0].x) * 0.25f;
        o0.y = (a0.y + (bfhi(p1.x) + bfhi(p2.x)) * sd + rn * sum[0].y) * 0.25f;
        o0.z = (a0.z + (bflo(p1.y) + bflo(p2.y)) * sd + rn * sum[1].x) * 0.25f;
        o0.w = (a0.w + (bfhi(p1.y) + bfhi(p2.y)) * sd + rn * sum[1].y) * 0.25f;
        o1.x = (a1.x + (bflo(p1.z) + bflo(p2.z)) * sd + rn * sum[2].x) * 0.25f;
        o1.y = (a1.y + (bfhi(p1.z) + bfhi(p2.z)) * sd + rn * sum[2].y) * 0.25f;
        o1.z = (a1.z + (bflo(p1.w) + bflo(p2.w)) * sd + rn * sum[3].x) * 0.25f;
        o1.w = (a1.w + (bfhi(p1.w) + bfhi(p2.w)) * sd + rn * sum[3].y) * 0.25f;
        size_t o4 = (size_t)n * 16 + q * 2;
        acc4[o4] = o0;
        acc4[o4 + 1] = o1;
    }
}

extern "C" void kernel_launch(void* const* d_in, const int* in_sizes, int n_in,
                              void* d_out, int out_size, void* d_ws, size_t ws_size,
                              hipStream_t stream) {
    const float* user = (const float*)d_in[0];
    const float* item = (const float*)d_in[1];
    const int*   ei   = (const int*)d_in[2];
    const int* row = ei;            // edge_index[0]
    const int* col = ei + N_EDGES;  // edge_index[1]

    char*  ws      = (char*)d_ws;
    int*   bhist   = (int*)(ws + OFF_BHIST);
    int*   bbase   = (int*)(ws + OFF_BBASE);
    int*   bcursor = (int*)(ws + OFF_BCURSOR);
    int2*  be      = (int2*)(ws + OFF_BE);
    float* rsqd    = (float*)(ws + OFF_RSQD);
    float* sdeg    = (float*)(ws + OFF_SDEG);
    int*   scol    = (int*)(ws + OFF_SCOL);
    char*  xA      = ws + OFF_XA;   // bf16 y-tables, (N+1) rows (row N = zeros)
    char*  xB      = ws + OFF_XB;
    unsigned* packed = (unsigned*)xB;  // alias: dead before pull layer 1 writes xB
    float* acc     = (float*)d_out;

    // CSR build (layer-invariant): hist -> scan(+dummy zero) -> partition -> fine(+y0)
    hipMemsetAsync(bhist, 0, N_BUCKETS * sizeof(int), stream);
    bhist_kernel<<<PART_BLOCKS, 1024, 0, stream>>>((const int4*)row, bhist);
    bscan_kernel<<<1, 1024, 0, stream>>>(bhist, bbase, bcursor, (uint2*)xA, (uint2*)xB);
    partition_kernel<<<PART_BLOCKS, 1024, 0, stream>>>((const int4*)row, (const int4*)col,
                                                       bcursor, packed);
    fine_kernel<<<N_BUCKETS, 256, 0, stream>>>(bbase, bhist, packed, be, rsqd, sdeg, scol,
                                               (const float4*)user, (const float4*)item,
                                               (uint2*)xA);

    // 3 pull layers
    const int grid = (N_NODES + 3) / 4;
    pull_kernel<<<grid, 256, 0, stream>>>(be, (const int2*)scol, rsqd,
        (const uint4*)xA, (uint4*)xB);
    pull_kernel<<<grid, 256, 0, stream>>>(be, (const int2*)scol, rsqd,
        (const uint4*)xB, (uint4*)xA);
    pull_last_kernel<<<grid, 256, 0, stream>>>(be, (const int2*)scol, rsqd, sdeg,
        (const uint4*)xA, (const uint4*)xB,
        (const float4*)user, (const float4*)item, (float4*)acc);
}